// Round 8
// baseline (782.913 us; speedup 1.0000x reference)
//
#include <hip/hip_runtime.h>
#include <hip/hip_bf16.h>

#define SEQ   2048
#define BATCH 256
#define HDIM  64
#define GDIM  256   // 4*H

typedef __attribute__((ext_vector_type(8))) short bf16x8;  // 8 bf16 = 4 VGPR
typedef __attribute__((ext_vector_type(4))) float f32x4;

static __device__ __forceinline__ unsigned short f2bf(float f) {
    return __builtin_bit_cast(unsigned short, __float2bfloat16(f));
}
static __device__ __forceinline__ float bf2f(unsigned short u) {
    return __builtin_bit_cast(float, ((unsigned int)u) << 16);
}

// MFMA LSTM. One workgroup per batch element, 4 waves; wave w owns units
// [16w,16w+16). Gates via mfma_16x16x32_bf16: A = h replicated over 16 rows
// (hi/lo bf16 split for ~fp32 recurrent precision), B = weight fragments
// (gate col g = 64t+16w+lc), bias in the C operand of the hi-chain.
// x rides the augmentation MFMA's k-slots 0..3 as [xhi0,xhi1,xlo0,xlo1].
// D layout (m89): col=lane&15, rows replicated -> lane reads acc[0] only.
// Activations/c/h fully in-lane (VALU+trans, off the MFMA pipe).
// Barrier = raw lgkmcnt(0)+s_barrier (global h stores stay in flight).
__global__ __launch_bounds__(256, 1) void lstm_mfma(
    const float* __restrict__ xin,   // [S,B,2]
    const float* __restrict__ Wih,   // [2,256]
    const float* __restrict__ Whh,   // [64,256]
    const float* __restrict__ bih,   // [256]
    const float* __restrict__ bhh,   // [256]
    float* __restrict__ out)         // fp32: hidden_seq [S,B,64] | h [B,64] | c [B,64]
{
    const int b   = blockIdx.x;
    const int tid = threadIdx.x;
    const int w   = tid >> 6;    // wave 0..3
    const int l   = tid & 63;    // lane
    const int lg  = l >> 4;      // k-group 0..3
    const int lc  = l & 15;      // tile column
    const int u   = 16 * w + lc; // hidden unit this lane handles

    __shared__ __align__(16) unsigned short v_hi[2][HDIM];  // h hi bf16, dbuf
    __shared__ __align__(16) unsigned short v_lo[2][HDIM];  // h lo bf16, dbuf
    __shared__ unsigned int xhi[SEQ];                       // packed (x0,x1) hi
    __shared__ unsigned int xlo[SEQ];                       // packed (x0,x1) lo

    // ---- stage x for this batch column: fp32 pair -> bf16 hi/lo pairs ----
    const float2* x2 = reinterpret_cast<const float2*>(xin);
    #pragma unroll
    for (int r = 0; r < SEQ / 256; ++r) {
        int s = r * 256 + tid;
        float2 v = x2[(size_t)s * BATCH + b];
        unsigned short h0 = f2bf(v.x), h1 = f2bf(v.y);
        unsigned short l0 = f2bf(v.x - bf2f(h0)), l1 = f2bf(v.y - bf2f(h1));
        xhi[s] = (unsigned int)h0 | ((unsigned int)h1 << 16);
        xlo[s] = (unsigned int)l0 | ((unsigned int)l1 << 16);
    }

    // ---- persistent weight fragments (B operand): gate g = 64t + 16w + lc,
    //      k = 32*kc + 8*lg + e. Chunk 2 rows 0..3 = [Wih0,Wih1,Wih0,Wih1]
    //      (hi and lo x share the same W columns).
    bf16x8 wf[4][3];
    f32x4  biasv[4];
    #pragma unroll
    for (int t = 0; t < 4; ++t) {
        const int g = 64 * t + 16 * w + lc;
        #pragma unroll
        for (int kc = 0; kc < 2; ++kc) {
            bf16x8 f;
            #pragma unroll
            for (int e = 0; e < 8; ++e) {
                int k = 32 * kc + 8 * lg + e;
                f[e] = (short)f2bf(Whh[k * GDIM + g]);
            }
            wf[t][kc] = f;
        }
        bf16x8 f2 = {0, 0, 0, 0, 0, 0, 0, 0};
        if (lg == 0) {
            f2[0] = (short)f2bf(Wih[0 * GDIM + g]);
            f2[1] = (short)f2bf(Wih[1 * GDIM + g]);
            f2[2] = f2[0];
            f2[3] = f2[1];
        }
        wf[t][2] = f2;
        const float bb = bih[g] + bhh[g];
        biasv[t] = (f32x4){bb, bb, bb, bb};
    }

    if (tid < HDIM) {
        v_hi[0][tid] = 0; v_hi[1][tid] = 0;
        v_lo[0][tid] = 0; v_lo[1][tid] = 0;
    }
    float c_state = 0.0f, hval = 0.0f;
    __syncthreads();

    const float L2E = 1.44269504088896340736f;
    const f32x4 zeroC = {0.0f, 0.0f, 0.0f, 0.0f};

    for (int s = 0; s < SEQ; ++s) {
        const int buf = s & 1;
        // A fragments: h vector, identical across the 16 replica rows
        bf16x8 ah0 = *reinterpret_cast<const bf16x8*>(&v_hi[buf][8 * lg]);       // k 0..31
        bf16x8 ah1 = *reinterpret_cast<const bf16x8*>(&v_hi[buf][32 + 8 * lg]);  // k 32..63
        bf16x8 al0 = *reinterpret_cast<const bf16x8*>(&v_lo[buf][8 * lg]);
        bf16x8 al1 = *reinterpret_cast<const bf16x8*>(&v_lo[buf][32 + 8 * lg]);
        bf16x8 ax = {0, 0, 0, 0, 0, 0, 0, 0};
        if (l < 16) {
            const unsigned int xh = xhi[s], xl = xlo[s];
            ax[0] = (short)(xh & 0xffffu);
            ax[1] = (short)(xh >> 16);
            ax[2] = (short)(xl & 0xffffu);
            ax[3] = (short)(xl >> 16);
        }

        // hi-chain (bias C, depth 2) || lo-chain (+x augmentation, depth 3)
        f32x4 accA[4], accB[4];
        #pragma unroll
        for (int t = 0; t < 4; ++t) {
            accA[t] = __builtin_amdgcn_mfma_f32_16x16x32_bf16(ah0, wf[t][0], biasv[t], 0, 0, 0);
            accB[t] = __builtin_amdgcn_mfma_f32_16x16x32_bf16(al0, wf[t][0], zeroC, 0, 0, 0);
        }
        #pragma unroll
        for (int t = 0; t < 4; ++t) {
            accA[t] = __builtin_amdgcn_mfma_f32_16x16x32_bf16(ah1, wf[t][1], accA[t], 0, 0, 0);
            accB[t] = __builtin_amdgcn_mfma_f32_16x16x32_bf16(al1, wf[t][1], accB[t], 0, 0, 0);
        }
        #pragma unroll
        for (int t = 0; t < 4; ++t) {
            accB[t] = __builtin_amdgcn_mfma_f32_16x16x32_bf16(ax, wf[t][2], accB[t], 0, 0, 0);
        }

        const float ip = accA[0][0] + accB[0][0];
        const float fp = accA[1][0] + accB[1][0];
        const float gp = accA[2][0] + accB[2][0];
        const float op = accA[3][0] + accB[3][0];

        // activations (in-lane): i,f,o sigmoid; g tanh
        const float iv = __builtin_amdgcn_rcpf(1.0f + __builtin_amdgcn_exp2f(-L2E * ip));
        const float fv = __builtin_amdgcn_rcpf(1.0f + __builtin_amdgcn_exp2f(-L2E * fp));
        const float gv = 2.0f * __builtin_amdgcn_rcpf(1.0f + __builtin_amdgcn_exp2f(-2.0f * L2E * gp)) - 1.0f;
        const float ov = __builtin_amdgcn_rcpf(1.0f + __builtin_amdgcn_exp2f(-L2E * op));

        c_state = fv * c_state + iv * gv;
        const float tc = 2.0f * __builtin_amdgcn_rcpf(1.0f + __builtin_amdgcn_exp2f(-2.0f * L2E * c_state)) - 1.0f;
        hval = ov * tc;

        if (l < 16) {
            const unsigned short hhi = f2bf(hval);
            const unsigned short hlo = f2bf(hval - bf2f(hhi));
            v_hi[buf ^ 1][u] = hhi;   // feed next step (~fp32 via hi/lo)
            v_lo[buf ^ 1][u] = hlo;
            out[(size_t)s * (BATCH * HDIM) + (size_t)b * HDIM + u] = hval;  // fire-and-forget
        }

        // LDS-only barrier: order h exchange WITHOUT draining global stores
        __builtin_amdgcn_sched_barrier(0);
        asm volatile("s_waitcnt lgkmcnt(0)\n\ts_barrier" ::: "memory");
        __builtin_amdgcn_sched_barrier(0);
    }

    // final h, c (fp32)
    if (l < 16) {
        const size_t HO = (size_t)SEQ * BATCH * HDIM;
        out[HO + (size_t)b * HDIM + u] = hval;
        out[HO + (size_t)BATCH * HDIM + (size_t)b * HDIM + u] = c_state;
    }
}

extern "C" void kernel_launch(void* const* d_in, const int* in_sizes, int n_in,
                              void* d_out, int out_size, void* d_ws, size_t ws_size,
                              hipStream_t stream) {
    const float* xin = (const float*)d_in[0];
    const float* Wih = (const float*)d_in[1];
    const float* Whh = (const float*)d_in[2];
    const float* bih = (const float*)d_in[3];
    const float* bhh = (const float*)d_in[4];
    float* out = (float*)d_out;

    lstm_mfma<<<BATCH, 256, 0, stream>>>(xin, Wih, Whh, bih, bhh, out);
}

// Round 9
// 514.392 us; speedup vs baseline: 1.5220x; 1.5220x over previous
//
#include <hip/hip_runtime.h>
#include <hip/hip_bf16.h>

#define SEQ   2048
#define BATCH 256
#define HDIM  64
#define GDIM  256   // 4*H

typedef __attribute__((ext_vector_type(8))) short bf16x8;  // 8 bf16 = 4 VGPR
typedef __attribute__((ext_vector_type(4))) float f32x4;

static __device__ __forceinline__ unsigned short f2bf(float f) {
    return __builtin_bit_cast(unsigned short, __float2bfloat16(f));
}

// MFMA LSTM, lean chain. One workgroup per batch element, 4 waves; wave w owns
// units [16w,16w+16). Per step: 8 mfma_16x16x32_bf16 in 4 parallel depth-2
// chains (gates t=i,f,g,o; bias in C), h fed back as plain bf16 via LDS.
// x@Wih + nothing-else on VALU in fp32 (12 FMAs, overlaps the ds_reads).
// D layout (validated r8): col=lane&15, rows replicated -> lane reads acc[0].
// Barrier = raw lgkmcnt(0)+s_barrier (global stores stay in flight).
__global__ __launch_bounds__(256, 1) void lstm_mfma2(
    const float* __restrict__ xin,   // [S,B,2]
    const float* __restrict__ Wih,   // [2,256]
    const float* __restrict__ Whh,   // [64,256]
    const float* __restrict__ bih,   // [256]
    const float* __restrict__ bhh,   // [256]
    float* __restrict__ out)         // fp32: hidden_seq [S,B,64] | h [B,64] | c [B,64]
{
    const int b   = blockIdx.x;
    const int tid = threadIdx.x;
    const int w   = tid >> 6;    // wave 0..3
    const int l   = tid & 63;    // lane
    const int lg  = l >> 4;      // k-group 0..3
    const int lc  = l & 15;      // tile column
    const int u   = 16 * w + lc; // hidden unit this lane handles

    __shared__ __align__(16) unsigned short v_hi[2][HDIM];  // h bf16, dbuf
    __shared__ float2 xf[SEQ];                              // staged x pairs (fp32)

    // ---- stage x for this batch column ----
    const float2* x2 = reinterpret_cast<const float2*>(xin);
    #pragma unroll
    for (int r = 0; r < SEQ / 256; ++r) {
        int s = r * 256 + tid;
        xf[s] = x2[(size_t)s * BATCH + b];
    }

    // ---- persistent weight fragments (B operand): gate g = 64t + 16w + lc,
    //      k = 32*kc + 8*lg + e ----
    bf16x8 wf[4][2];
    f32x4  biasv[4];
    float  wx0[4], wx1[4];
    #pragma unroll
    for (int t = 0; t < 4; ++t) {
        const int g = 64 * t + 16 * w + lc;
        #pragma unroll
        for (int kc = 0; kc < 2; ++kc) {
            bf16x8 f;
            #pragma unroll
            for (int e = 0; e < 8; ++e) {
                int k = 32 * kc + 8 * lg + e;
                f[e] = (short)f2bf(Whh[k * GDIM + g]);
            }
            wf[t][kc] = f;
        }
        wx0[t] = Wih[0 * GDIM + g];
        wx1[t] = Wih[1 * GDIM + g];
        const float bb = bih[g] + bhh[g];
        biasv[t] = (f32x4){bb, bb, bb, bb};
    }

    if (tid < HDIM) { v_hi[0][tid] = 0; v_hi[1][tid] = 0; }
    float c_state = 0.0f, hval = 0.0f;
    __syncthreads();

    const float L2E = 1.44269504088896340736f;

    for (int s = 0; s < SEQ; ++s) {
        const int buf = s & 1;
        // A fragments: h vector, identical across the 16 replica rows
        bf16x8 ah0 = *reinterpret_cast<const bf16x8*>(&v_hi[buf][8 * lg]);       // k 0..31
        bf16x8 ah1 = *reinterpret_cast<const bf16x8*>(&v_hi[buf][32 + 8 * lg]);  // k 32..63

        // x contribution in fp32 on VALU (overlaps the ds_reads)
        const float2 xv = xf[s];
        float xb[4];
        #pragma unroll
        for (int t = 0; t < 4; ++t)
            xb[t] = wx0[t] * xv.x + wx1[t] * xv.y;

        // 4 parallel depth-2 MFMA chains (bias in C)
        f32x4 acc[4];
        #pragma unroll
        for (int t = 0; t < 4; ++t)
            acc[t] = __builtin_amdgcn_mfma_f32_16x16x32_bf16(ah0, wf[t][0], biasv[t], 0, 0, 0);
        #pragma unroll
        for (int t = 0; t < 4; ++t)
            acc[t] = __builtin_amdgcn_mfma_f32_16x16x32_bf16(ah1, wf[t][1], acc[t], 0, 0, 0);

        const float ip = acc[0][0] + xb[0];
        const float fp = acc[1][0] + xb[1];
        const float gp = acc[2][0] + xb[2];
        const float op = acc[3][0] + xb[3];

        // activations (in-lane): i,f,o sigmoid; g tanh
        const float iv = __builtin_amdgcn_rcpf(1.0f + __builtin_amdgcn_exp2f(-L2E * ip));
        const float fv = __builtin_amdgcn_rcpf(1.0f + __builtin_amdgcn_exp2f(-L2E * fp));
        const float gv = 2.0f * __builtin_amdgcn_rcpf(1.0f + __builtin_amdgcn_exp2f(-2.0f * L2E * gp)) - 1.0f;
        const float ov = __builtin_amdgcn_rcpf(1.0f + __builtin_amdgcn_exp2f(-L2E * op));

        c_state = fv * c_state + iv * gv;
        const float tc = 2.0f * __builtin_amdgcn_rcpf(1.0f + __builtin_amdgcn_exp2f(-2.0f * L2E * c_state)) - 1.0f;
        hval = ov * tc;

        if (l < 16) {
            v_hi[buf ^ 1][u] = f2bf(hval);   // feed next step (bf16)
            out[(size_t)s * (BATCH * HDIM) + (size_t)b * HDIM + u] = hval;  // fire-and-forget
        }

        // LDS-only barrier: order h exchange WITHOUT draining global stores
        __builtin_amdgcn_sched_barrier(0);
        asm volatile("s_waitcnt lgkmcnt(0)\n\ts_barrier" ::: "memory");
        __builtin_amdgcn_sched_barrier(0);
    }

    // final h, c (fp32)
    if (l < 16) {
        const size_t HO = (size_t)SEQ * BATCH * HDIM;
        out[HO + (size_t)b * HDIM + u] = hval;
        out[HO + (size_t)BATCH * HDIM + (size_t)b * HDIM + u] = c_state;
    }
}

extern "C" void kernel_launch(void* const* d_in, const int* in_sizes, int n_in,
                              void* d_out, int out_size, void* d_ws, size_t ws_size,
                              hipStream_t stream) {
    const float* xin = (const float*)d_in[0];
    const float* Wih = (const float*)d_in[1];
    const float* Whh = (const float*)d_in[2];
    const float* bih = (const float*)d_in[3];
    const float* bhh = (const float*)d_in[4];
    float* out = (float*)d_out;

    lstm_mfma2<<<BATCH, 256, 0, stream>>>(xin, Wih, Whh, bih, bhh, out);
}